// Round 4
// baseline (4748.596 us; speedup 1.0000x reference)
//
#include <hip/hip_runtime.h>
#include <hip/hip_fp16.h>

// LSTM B=64, T=1024, I=256, H=512 — persistent weight-stationary.
//
// 128 WGs x 256 thr. Wave w of WG g: batch rows [16w,16w+16) x 16 gate cols
// (h-cols [4g,4g+4)). Weights [768,16] f16 in registers (24 B-frags).
// Per step: poll (wave 0 only) 128 unpadded per-WG flags (8 cache lines),
// __syncthreads release; agent-scope u64 h loads (L3-coherent); 16 h-MFMAs;
// activations + register c-state; shfl-transpose; 16 coalesced u64 agent
// stores; vmcnt(0); __syncthreads; tid0 stores flag=t+1 (plain relaxed store,
// no RMW); x-part GEMM of t+1 computed in the barrier shadow.
//
// Double-buffer safety: flag[g]=t implies WG g's step t-1 h-loads AND h-stores
// drained (vmcnt(0) before sync before flag), so writing buf[(t+1)&1] at step
// t (only after seeing all flags>=t) cannot race step t-1 readers of that buf.
//
// h layout: [2][128 col-blocks][64 rows] u64 (u64 = 4 consecutive cols f16).

#define T_STEPS 1024
#define BATCH   64
#define ISZ     256
#define HSZ     512
#define NWG     128
#define NTHR    256
#define HB4     ((BATCH * HSZ) / 4)   // u64 per h buffer (8192)

typedef _Float16 half8  __attribute__((ext_vector_type(8)));
typedef _Float16 half4  __attribute__((ext_vector_type(4)));
typedef float    floatx4 __attribute__((ext_vector_type(4)));
typedef unsigned long long u64;

#define LD_AGENT(p)     __hip_atomic_load((p), __ATOMIC_RELAXED, __HIP_MEMORY_SCOPE_AGENT)
#define ST_AGENT(p, v)  __hip_atomic_store((p), (v), __ATOMIC_RELAXED, __HIP_MEMORY_SCOPE_AGENT)

__device__ __forceinline__ float fast_sigmoid(float x) {
    return 1.0f / (1.0f + __expf(-x));
}
__device__ __forceinline__ float fast_tanh(float x) {
    return 1.0f - 2.0f / (__expf(2.0f * x) + 1.0f);
}

__global__ __launch_bounds__(NTHR, 1) void lstm_persist(
    const float* __restrict__ x,
    const float* __restrict__ Wf, const float* __restrict__ bfv,
    const float* __restrict__ Wi, const float* __restrict__ biv,
    const float* __restrict__ Wc, const float* __restrict__ bcv,
    const float* __restrict__ Wo, const float* __restrict__ bov,
    u64* __restrict__ hbuf4, unsigned* __restrict__ flags)
{
    const int g    = blockIdx.x;        // 0..127
    const int tid  = threadIdx.x;
    const int w    = tid >> 6;          // wave -> row-block [16w,16w+16)
    const int l    = tid & 63;
    const int lj   = l & 15;
    const int lk   = l >> 4;
    const int gate = lj >> 2;           // 0=f 1=i 2=c~ 3=o
    const int jc   = lj & 3;
    const int hc   = (g << 2) + jc;     // h column
    const int row0 = w << 4;
    const int arow = row0 + lj;         // A-operand batch row

    const float* Wg = (gate == 0) ? Wf : (gate == 1) ? Wi : (gate == 2) ? Wc : Wo;
    const float* bg = (gate == 0) ? bfv : (gate == 1) ? biv : (gate == 2) ? bcv : bov;

    // Weight fragments, resident for all 1024 steps. k in fragment =
    // kf*32 + lk*8 + e; A-fragments use the identical k mapping.
    half8 Bfrag[24];
    #pragma unroll
    for (int kf = 0; kf < 24; ++kf) {
        half8 v;
        #pragma unroll
        for (int e = 0; e < 8; ++e) {
            int k = (kf << 5) + (lk << 3) + e;
            v[e] = (_Float16)Wg[(size_t)k * HSZ + hc];
        }
        Bfrag[kf] = v;
    }
    const float bias = bg[hc];
    float cst[4] = {0.f, 0.f, 0.f, 0.f};

    const u64* fl = (const u64*)flags;   // 64 u64 = 128 u32 flags, 8 lines

    // x-part for t=0
    floatx4 accx = {0.f, 0.f, 0.f, 0.f};
    {
        const float* xr = x + (size_t)arow * T_STEPS * ISZ + (lk << 3);
        #pragma unroll
        for (int kf = 0; kf < 8; ++kf) {
            floatx4 x0 = *(const floatx4*)(xr + (kf << 5));
            floatx4 x1 = *(const floatx4*)(xr + (kf << 5) + 4);
            half8 a;
            a[0] = (_Float16)x0[0]; a[1] = (_Float16)x0[1];
            a[2] = (_Float16)x0[2]; a[3] = (_Float16)x0[3];
            a[4] = (_Float16)x1[0]; a[5] = (_Float16)x1[1];
            a[6] = (_Float16)x1[2]; a[7] = (_Float16)x1[3];
            accx = __builtin_amdgcn_mfma_f32_16x16x32_f16(a, Bfrag[kf], accx, 0, 0, 0);
        }
    }

    for (int t = 0; t < T_STEPS; ++t) {
        floatx4 acc0, acc1;
        #pragma unroll
        for (int e = 0; e < 4; ++e) { acc0[e] = accx[e] + bias; acc1[e] = 0.f; }

        if (t > 0) {
            // wave 0 polls all 128 per-WG flags (>= t); others wait at barrier
            if (w == 0) {
                const unsigned tgt = (unsigned)t;
                while (true) {
                    u64 v = LD_AGENT(fl + l);
                    if (__all(((unsigned)v >= tgt) && ((unsigned)(v >> 32) >= tgt))) break;
                    __builtin_amdgcn_s_sleep(1);
                }
            }
            __syncthreads();

            const u64* hr = hbuf4 + (size_t)(t & 1) * HB4 + arow;
            u64 hl[32];
            #pragma unroll
            for (int kf = 0; kf < 16; ++kf) {
                const int c0 = kf * 8 + lk * 2;
                hl[2 * kf]     = LD_AGENT(hr + (size_t)c0 * BATCH);
                hl[2 * kf + 1] = LD_AGENT(hr + (size_t)(c0 + 1) * BATCH);
            }
            // two independent 8-deep MFMA chains
            #pragma unroll
            for (int kf = 0; kf < 16; kf += 2) {
                union { u64 u[2]; half8 h; } a0, a1;
                a0.u[0] = hl[2 * kf];     a0.u[1] = hl[2 * kf + 1];
                a1.u[0] = hl[2 * kf + 2]; a1.u[1] = hl[2 * kf + 3];
                acc0 = __builtin_amdgcn_mfma_f32_16x16x32_f16(a0.h, Bfrag[8 + kf], acc0, 0, 0, 0);
                acc1 = __builtin_amdgcn_mfma_f32_16x16x32_f16(a1.h, Bfrag[9 + kf], acc1, 0, 0, 0);
            }
        }

        // activations (gate uniform per lane)
        floatx4 act;
        if (gate == 2) {
            #pragma unroll
            for (int e = 0; e < 4; ++e) act[e] = fast_tanh(acc0[e] + acc1[e]);
        } else {
            #pragma unroll
            for (int e = 0; e < 4; ++e) act[e] = fast_sigmoid(acc0[e] + acc1[e]);
        }

        // broadcast 4 gate values within each (lk,jc) quartet; replicated c-state
        const int base = l & ~12;
        float hv[4];
        #pragma unroll
        for (int e = 0; e < 4; ++e) {
            float vf = __shfl(act[e], base);
            float vi = __shfl(act[e], base + 4);
            float vc = __shfl(act[e], base + 8);
            float vo = __shfl(act[e], base + 12);
            float c  = vf * cst[e] + vi * vc;
            cst[e] = c;
            hv[e] = vo * fast_tanh(c);
        }

        // shfl-transpose: lane L<16 gathers row row0+L, cols 4g..4g+4 (u64)
        half4 outv;
        #pragma unroll
        for (int col = 0; col < 4; ++col) {
            const int src = ((l & 15) >> 2) * 16 + col;
            float sel = 0.f;
            #pragma unroll
            for (int e = 0; e < 4; ++e) {
                float tmp = __shfl(hv[e], src);
                if ((l & 3) == e) sel = tmp;
            }
            outv[col] = (_Float16)sel;
        }
        u64* hw = hbuf4 + (size_t)((t + 1) & 1) * HB4 + (size_t)g * BATCH + row0;
        if (l < 16) {
            union { half4 h; u64 u; } pk; pk.h = outv;
            ST_AGENT(hw + l, pk.u);
        }
        asm volatile("s_waitcnt vmcnt(0)" ::: "memory");   // h stores at L3
        __syncthreads();                                   // all 4 waves drained
        if (tid == 0) ST_AGENT(&flags[g], (unsigned)(t + 1));  // plain store, no RMW

        // x-part of step t+1 in the barrier shadow
        if (t + 1 < T_STEPS) {
            floatx4 az = {0.f, 0.f, 0.f, 0.f};
            const float* xr = x + ((size_t)arow * T_STEPS + (t + 1)) * ISZ + (lk << 3);
            #pragma unroll
            for (int kf = 0; kf < 8; ++kf) {
                floatx4 x0 = *(const floatx4*)(xr + (kf << 5));
                floatx4 x1 = *(const floatx4*)(xr + (kf << 5) + 4);
                half8 a;
                a[0] = (_Float16)x0[0]; a[1] = (_Float16)x0[1];
                a[2] = (_Float16)x0[2]; a[3] = (_Float16)x0[3];
                a[4] = (_Float16)x1[0]; a[5] = (_Float16)x1[1];
                a[6] = (_Float16)x1[2]; a[7] = (_Float16)x1[3];
                az = __builtin_amdgcn_mfma_f32_16x16x32_f16(a, Bfrag[kf], az, 0, 0, 0);
            }
            accx = az;
        }
    }
}

// final h is in hbuf4[0] (t=1023 writes buffer (1023+1)&1 = 0)
__global__ void out_proj(const u64* __restrict__ hb4, const float* __restrict__ Wfc,
                         const float* __restrict__ bfc, float* __restrict__ out)
{
    const int b = blockIdx.x;      // 64
    const int l = threadIdx.x;     // 64
    float s = 0.f;
    #pragma unroll
    for (int j = 0; j < 2; ++j) {
        const int c4 = l + (j << 6);
        union { u64 u; half4 h; } v;
        v.u = hb4[(size_t)c4 * BATCH + b];
        #pragma unroll
        for (int q = 0; q < 4; ++q)
            s += (float)v.h[q] * Wfc[c4 * 4 + q];
    }
    #pragma unroll
    for (int off = 32; off; off >>= 1) s += __shfl_down(s, off);
    if (l == 0) out[b] = s + bfc[0];
}

extern "C" void kernel_launch(void* const* d_in, const int* in_sizes, int n_in,
                              void* d_out, int out_size, void* d_ws, size_t ws_size,
                              hipStream_t stream)
{
    const float* x   = (const float*)d_in[0];
    const float* Wf  = (const float*)d_in[1];
    const float* bf  = (const float*)d_in[2];
    const float* Wi  = (const float*)d_in[3];
    const float* bi  = (const float*)d_in[4];
    const float* Wc  = (const float*)d_in[5];
    const float* bc  = (const float*)d_in[6];
    const float* Wo  = (const float*)d_in[7];
    const float* bo  = (const float*)d_in[8];
    const float* Wfc = (const float*)d_in[9];
    const float* bfc = (const float*)d_in[10];

    u64* hbuf4 = (u64*)d_ws;                                            // 128 KB
    unsigned* flags = (unsigned*)((char*)d_ws + 2 * HB4 * sizeof(u64)); // 512 B

    // flags restart at 0 every launch (monotonic targets, graph-replay safe)
    hipMemsetAsync(flags, 0, NWG * sizeof(unsigned), stream);

    void* args[] = { (void*)&x, (void*)&Wf, (void*)&bf, (void*)&Wi, (void*)&bi,
                     (void*)&Wc, (void*)&bc, (void*)&Wo, (void*)&bo,
                     (void*)&hbuf4, (void*)&flags };
    hipLaunchCooperativeKernel((void*)lstm_persist, dim3(NWG), dim3(NTHR),
                               args, 0, stream);

    out_proj<<<dim3(BATCH), dim3(64), 0, stream>>>(hbuf4, Wfc, bfc, (float*)d_out);
}